// Round 1
// baseline (109.677 us; speedup 1.0000x reference)
//
#include <hip/hip_runtime.h>
#include <math.h>

#define BATCH 8
#define NSLOT 256
#define DDIM  256
#define HID   128
#define NREL  8

// ---------------------------------------------------------------------------
// Kernel 1: per-slot projection.
// P[row][0:128]   = slots_row @ W1[:256,:]  + b1   (proj_i, bias folded)
// P[row][128:256] = slots_row @ W1[256:,:]         (proj_j, no bias)
// row = b*256 + n, 2048 rows total. 256 blocks x 256 threads, 8 rows/block.
// Thread owns one output column c; slots values are wave-uniform -> s_load.
// ---------------------------------------------------------------------------
__global__ __launch_bounds__(256) void proj_kernel(
    const float* __restrict__ slots, const float* __restrict__ W1,
    const float* __restrict__ b1, float* __restrict__ P) {
  const int tid  = threadIdx.x;
  const int row0 = blockIdx.x * 8;
  const int c    = tid;  // 0..255
  const bool isP1 = (c < HID);
  const float* Wcol = isP1 ? (W1 + c) : (W1 + DDIM * HID + (c - HID));
  const float bias = isP1 ? b1[c] : 0.0f;

  float acc[8];
#pragma unroll
  for (int r = 0; r < 8; ++r) acc[r] = bias;

  const float* srow = slots + (size_t)row0 * DDIM;
  for (int d = 0; d < DDIM; d += 4) {
#pragma unroll
    for (int dd = 0; dd < 4; ++dd) {
      const float w = Wcol[(size_t)(d + dd) * HID];  // coalesced across lanes
#pragma unroll
      for (int r = 0; r < 8; ++r) {
        acc[r] = fmaf(srow[r * DDIM + d + dd], w, acc[r]);  // srow uniform -> s_load
      }
    }
  }
#pragma unroll
  for (int r = 0; r < 8; ++r) {
    P[(size_t)(row0 + r) * 256 + c] = acc[r];
  }
}

// ---------------------------------------------------------------------------
// Kernel 2: pair grid.
// out[b,i,j,r] = sigmoid( sum_k relu(P[b,i,k] + P[b,j,128+k]) * W2[k,r] + b2[r] )
// Grid: (j-tile 8, i-tile 8, b 8); 32x32 pair tile per block, 256 threads,
// each thread computes 2x2 pairs x 8 rels. Pi/Pj staged in LDS (stride 132:
// 16B-aligned, max 2-way bank aliasing = free). W2/b2 uniform -> scalar loads.
// ---------------------------------------------------------------------------
__global__ __launch_bounds__(256) void pair_kernel(
    const float* __restrict__ P, const float* __restrict__ W2,
    const float* __restrict__ b2, float* __restrict__ out) {
  __shared__ float Pi[32 * 132];
  __shared__ float Pj[32 * 132];

  const int tid = threadIdx.x;
  const int j0  = blockIdx.x * 32;
  const int i0  = blockIdx.y * 32;
  const int b   = blockIdx.z;
  const float* Pb = P + (size_t)b * NSLOT * 256;

  // Cooperative stage: 32 rows x 128 floats each side, float4 loads.
#pragma unroll
  for (int t = 0; t < 4; ++t) {
    const int idx = tid + t * 256;
    const int r   = idx >> 5;          // 0..31
    const int c4  = (idx & 31) * 4;    // 0..124
    *(float4*)&Pi[r * 132 + c4] = *(const float4*)&Pb[(size_t)(i0 + r) * 256 + c4];
    *(float4*)&Pj[r * 132 + c4] = *(const float4*)&Pb[(size_t)(j0 + r) * 256 + 128 + c4];
  }
  __syncthreads();

  const int tj = tid & 15;
  const int ti = tid >> 4;

  float acc[2][2][NREL];
#pragma unroll
  for (int ii = 0; ii < 2; ++ii)
#pragma unroll
    for (int jj = 0; jj < 2; ++jj)
#pragma unroll
      for (int r = 0; r < NREL; ++r) acc[ii][jj][r] = 0.0f;

  for (int kc = 0; kc < 32; ++kc) {
    const float4 a0 = *(const float4*)&Pi[(ti)      * 132 + kc * 4];
    const float4 a1 = *(const float4*)&Pi[(ti + 16) * 132 + kc * 4];
    const float4 c0 = *(const float4*)&Pj[(tj)      * 132 + kc * 4];
    const float4 c1 = *(const float4*)&Pj[(tj + 16) * 132 + kc * 4];
    const float ap0[4] = {a0.x, a0.y, a0.z, a0.w};
    const float ap1[4] = {a1.x, a1.y, a1.z, a1.w};
    const float cp0[4] = {c0.x, c0.y, c0.z, c0.w};
    const float cp1[4] = {c1.x, c1.y, c1.z, c1.w};
#pragma unroll
    for (int kk = 0; kk < 4; ++kk) {
      const int k = kc * 4 + kk;
      const float h00 = fmaxf(ap0[kk] + cp0[kk], 0.0f);
      const float h01 = fmaxf(ap0[kk] + cp1[kk], 0.0f);
      const float h10 = fmaxf(ap1[kk] + cp0[kk], 0.0f);
      const float h11 = fmaxf(ap1[kk] + cp1[kk], 0.0f);
#pragma unroll
      for (int r = 0; r < NREL; ++r) {
        const float w = W2[k * NREL + r];  // uniform index -> s_load
        acc[0][0][r] = fmaf(h00, w, acc[0][0][r]);
        acc[0][1][r] = fmaf(h01, w, acc[0][1][r]);
        acc[1][0][r] = fmaf(h10, w, acc[1][0][r]);
        acc[1][1][r] = fmaf(h11, w, acc[1][1][r]);
      }
    }
  }

  // Epilogue: bias, sigmoid, coalesced float4 stores.
#pragma unroll
  for (int ii = 0; ii < 2; ++ii) {
#pragma unroll
    for (int jj = 0; jj < 2; ++jj) {
      const int i = i0 + ti + 16 * ii;
      const int j = j0 + tj + 16 * jj;
      float res[8] __attribute__((aligned(16)));
#pragma unroll
      for (int r = 0; r < NREL; ++r) {
        const float x = acc[ii][jj][r] + b2[r];  // b2 uniform -> s_load
        res[r] = 1.0f / (1.0f + __expf(-x));
      }
      float* o = out + (((size_t)b * NSLOT + i) * NSLOT + j) * NREL;
      *(float4*)&o[0] = *(const float4*)&res[0];
      *(float4*)&o[4] = *(const float4*)&res[4];
    }
  }
}

extern "C" void kernel_launch(void* const* d_in, const int* in_sizes, int n_in,
                              void* d_out, int out_size, void* d_ws, size_t ws_size,
                              hipStream_t stream) {
  const float* slots = (const float*)d_in[0];  // [8,256,256]
  const float* W1    = (const float*)d_in[1];  // [512,128]
  const float* b1    = (const float*)d_in[2];  // [128]
  const float* W2    = (const float*)d_in[3];  // [128,8]
  const float* b2    = (const float*)d_in[4];  // [8]
  float* out = (float*)d_out;                  // [8,256,256,8]
  float* P   = (float*)d_ws;                   // [2048][256] fp32 = 2 MB scratch

  proj_kernel<<<dim3(BATCH * NSLOT / 8), 256, 0, stream>>>(slots, W1, b1, P);
  pair_kernel<<<dim3(NSLOT / 32, NSLOT / 32, BATCH), 256, 0, stream>>>(P, W2, b2, out);
}